// Round 19
// baseline (4282.798 us; speedup 1.0000x reference)
//
#include <hip/hip_runtime.h>
#include <math.h>

#define BB 64
#define TT 512
#define FF 32
#define HH 512
#define OO 680

typedef _Float16 half8 __attribute__((ext_vector_type(8)));
typedef float f32x4 __attribute__((ext_vector_type(4)));

// ---- ws layout: act slabs in MFMA-B-fragment tile order ----
// h1: 2 slots (epoch parity). c1: RING OF 4 (L2 is skewed by 2 epochs).
// h2: 2 slots (epoch parity).
#define H1S_OFF 0u          // 2 x 65536
#define C1S_OFF 131072u     // 4 x 65536
#define H2S_OFF 393216u     // 2 x 90112
#define BAR_OFF 573440u     // 64 epoch slots (4 lines, store-only)
#define MEMSET_BYTES 573696u

#define NBLK 64
#define LDS_BYTES 151552u   // L1 weights 34KB + L2 weights 114KB
#define L2W_OFF 34816u

__device__ __forceinline__ float sigf(float x) { return 1.f / (1.f + expf(-x)); }

__device__ __forceinline__ unsigned al32(const unsigned* p) {
    return __hip_atomic_load(p, __ATOMIC_RELAXED, __HIP_MEMORY_SCOPE_AGENT);
}
__device__ __forceinline__ unsigned long long aload8(const void* p) {
    return __hip_atomic_load((const unsigned long long*)p, __ATOMIC_RELAXED, __HIP_MEMORY_SCOPE_AGENT);
}
__device__ __forceinline__ void astore8(void* p, unsigned long long v) {
    __hip_atomic_store((unsigned long long*)p, v, __ATOMIC_RELAXED, __HIP_MEMORY_SCOPE_AGENT);
}
__device__ __forceinline__ void astore32(unsigned* p, unsigned v) {
    __hip_atomic_store(p, v, __ATOMIC_RELAXED, __HIP_MEMORY_SCOPE_AGENT);
}
__device__ __forceinline__ half8 ld_act(const char* p) {
    union { unsigned long long u[2]; half8 h; } t;
    t.u[0] = aload8(p); t.u[1] = aload8(p + 8);
    return t.h;
}
__device__ __forceinline__ unsigned pack2h(float a, float b) {
    union { _Float16 h[2]; unsigned u; } t;
    t.h[0] = (_Float16)a; t.h[1] = (_Float16)b; return t.u;
}
__device__ __forceinline__ unsigned long long pack4h(float a, float b, float c, float d) {
    union { _Float16 h[4]; unsigned long long u; } t;
    t.h[0] = (_Float16)a; t.h[1] = (_Float16)b; t.h[2] = (_Float16)c; t.h[3] = (_Float16)d;
    return t.u;
}
__device__ __forceinline__ size_t slab_waddr(int cc, int b) {
    return (size_t)((cc >> 5) * 4 + (b >> 4)) * 1024
         + (size_t)((((cc >> 3) & 3) * 16 + (b & 15))) * 16
         + (size_t)(cc & 7) * 2;
}

// Merged persistent MFMA kernel, 64 blocks x 256 threads, ONE sync domain.
// Epoch s: L1 step s (s<TT) and L2 step s-2 (s>=2). c1 feed-forward edge at
// distance 2 => its 16 tiles + 48 MFMAs are prefetched BEFORE the wait
// (visibility guaranteed by the PREVIOUS epoch's wait; no poll needed).
// Post-wait path: h1 (16 tiles, 32 MFMA) + h2 (22 tiles, 66 MFMA) only.
__global__ __launch_bounds__(256, 1)
void rnn_merged(const float* __restrict__ data,
    const float* __restrict__ Wih1, const float* __restrict__ Whh1,
    const float* __restrict__ bih1, const float* __restrict__ bhh1,
    const float* __restrict__ Wih2, const float* __restrict__ Whh2,
    const float* __restrict__ bih2, const float* __restrict__ bhh2,
    char* __restrict__ wsb, float* __restrict__ out)
{
    extern __shared__ char lds[];
    const int tid = threadIdx.x, wv = tid >> 6, l = tid & 63;
    const int hi = l >> 4, lo = l & 15;
    const int bk = blockIdx.x;
    unsigned* bar = (unsigned*)(wsb + BAR_OFF);
    const int b = wv * 16 + lo;                 // this lane's batch

    // ---- one-time: convert weights fp32 -> fp16 into LDS (A-fragment tiles) ----
    for (int u = tid; u < 34 * 256; u += 256) {
        const int tt = u >> 8, w = u & 255;
        const int ks = tt >> 1, q = tt & 1;
        const int ll = w >> 2, jj = w & 3;
        const int fq = q * 16 + (ll & 15);
        const int col = bk * 8 + (fq >> 2);
        const int gate = fq & 3;
        const int grow = gate * HH + col;
        const int k = ks * 32 + (ll >> 4) * 8 + jj * 2;
        const float v0 = (k < FF)     ? Wih1[(size_t)grow * FF + k]     : Whh1[(size_t)grow * HH + k - FF];
        const float v1 = (k + 1 < FF) ? Wih1[(size_t)grow * FF + k + 1] : Whh1[(size_t)grow * HH + k + 1 - FF];
        ((unsigned*)lds)[tt * 256 + w] = pack2h(v0, v1);
    }
    for (int u = tid; u < 114 * 256; u += 256) {
        const int tt = u >> 8, w = u & 255;
        const int ks = tt / 3, q = tt - ks * 3;
        const int ll = w >> 2, jj = w & 3;
        const int fq = q * 16 + (ll & 15);
        const int col = bk * 12 + (fq >> 2);
        const int gate = fq & 3;
        const int k = ks * 32 + (ll >> 4) * 8 + jj * 2;
        float v0 = 0.f, v1 = 0.f;
        if (col < OO) {
            if (k < HH) v0 = Wih2[((size_t)gate * OO + col) * HH + k];
            else if (k < 1192) v0 = Whh2[((size_t)gate * OO + col) * OO + k - HH];
            if (k + 1 < HH) v1 = Wih2[((size_t)gate * OO + col) * HH + k + 1];
            else if (k + 1 < 1192) v1 = Whh2[((size_t)gate * OO + col) * OO + k + 1 - HH];
        }
        ((unsigned*)(lds + L2W_OFF))[tt * 256 + w] = pack2h(v0, v1);
    }
    __syncthreads();

    // ---- bias hoist: lane-local ----
    float bs1[2][4], bs2[3][4];
    #pragma unroll
    for (int q = 0; q < 2; ++q) {
        const int col = bk * 8 + q * 4 + hi;
        #pragma unroll
        for (int g = 0; g < 4; ++g) bs1[q][g] = bih1[g * HH + col] + bhh1[g * HH + col];
    }
    #pragma unroll
    for (int q = 0; q < 3; ++q) {
        const int col = bk * 12 + q * 4 + hi;
        const bool ok = col < OO;
        #pragma unroll
        for (int g = 0; g < 4; ++g) bs2[q][g] = ok ? (bih2[g * OO + col] + bhh2[g * OO + col]) : 0.f;
    }
    float cr1[2] = {0.f, 0.f};
    float cr2[3] = {0.f, 0.f, 0.f};

    for (int s = 0; s <= TT + 1; ++s) {
        const int wr = s & 1, rd = wr ^ 1;      // h1/h2 slot parity
        const bool doL1 = (s < TT);
        const bool doL2 = (s >= 2);

        f32x4 a10 = {0,0,0,0}, a11 = {0,0,0,0};
        f32x4 a20 = {0,0,0,0}, a21 = {0,0,0,0}, a22 = {0,0,0,0};

        // ======== PREFETCH SECTION (no wait needed) ========
        // c1(s-2): published 2 epochs ago; visibility covered by previous wait.
        if (doL2) {
            const char* c1p = wsb + C1S_OFF + (size_t)((s - 2) & 3) * 65536u + (size_t)l * 16;
            half8 bc[16];
            #pragma unroll
            for (int ks = 0; ks < 16; ++ks) bc[ks] = ld_act(c1p + (size_t)(ks * 4 + wv) * 1024);
            #pragma unroll
            for (int ks = 0; ks < 16; ++ks) {
                const char* at = lds + L2W_OFF + (size_t)(ks * 3) * 1024 + (size_t)l * 16;
                a20 = __builtin_amdgcn_mfma_f32_16x16x32_f16(*(const half8*)(at       ), bc[ks], a20, 0, 0, 0);
                a21 = __builtin_amdgcn_mfma_f32_16x16x32_f16(*(const half8*)(at + 1024), bc[ks], a21, 0, 0, 0);
                a22 = __builtin_amdgcn_mfma_f32_16x16x32_f16(*(const half8*)(at + 2048), bc[ks], a22, 0, 0, 0);
            }
        }
        // x-part (read-only input)
        if (doL1) {
            const float* xp = data + (size_t)b * (TT * FF) + (size_t)s * FF + hi * 8;
            const float4 xa = *(const float4*)xp;
            const float4 xb4 = *(const float4*)(xp + 4);
            half8 bx;
            bx[0] = (_Float16)xa.x; bx[1] = (_Float16)xa.y; bx[2] = (_Float16)xa.z; bx[3] = (_Float16)xa.w;
            bx[4] = (_Float16)xb4.x; bx[5] = (_Float16)xb4.y; bx[6] = (_Float16)xb4.z; bx[7] = (_Float16)xb4.w;
            a10 = __builtin_amdgcn_mfma_f32_16x16x32_f16(*(const half8*)(lds + (size_t)l * 16), bx, a10, 0, 0, 0);
            a11 = __builtin_amdgcn_mfma_f32_16x16x32_f16(*(const half8*)(lds + 1024 + (size_t)l * 16), bx, a11, 0, 0, 0);
        }

        // ======== THE single wait: all 64 slots >= s ========
        if (s > 0) {
            if (wv == 0) {
                for (;;) {
                    unsigned v = al32(bar + l);
                    #pragma unroll
                    for (int off = 32; off > 0; off >>= 1) {
                        const unsigned o = __shfl_xor(v, off);
                        v = (o < v) ? o : v;
                    }
                    if (v >= (unsigned)s) break;
                    __builtin_amdgcn_s_sleep(1);
                }
            }
            __syncthreads();
        }
        float pend[4]; float* pendP = nullptr;

        // ======== POST-WAIT: L1 h1-part, step s ========
        if (doL1) {
            const char* h1p = wsb + H1S_OFF + (size_t)rd * 65536u + (size_t)l * 16;
            half8 bh[16];
            #pragma unroll
            for (int ks = 0; ks < 16; ++ks) bh[ks] = ld_act(h1p + (size_t)(ks * 4 + wv) * 1024);
            #pragma unroll
            for (int ks = 1; ks <= 16; ++ks) {
                a10 = __builtin_amdgcn_mfma_f32_16x16x32_f16(*(const half8*)(lds + (size_t)(ks * 2) * 1024 + (size_t)l * 16), bh[ks - 1], a10, 0, 0, 0);
                a11 = __builtin_amdgcn_mfma_f32_16x16x32_f16(*(const half8*)(lds + (size_t)(ks * 2 + 1) * 1024 + (size_t)l * 16), bh[ks - 1], a11, 0, 0, 0);
            }
            float cn1[2], hn1[2];
            #pragma unroll
            for (int q = 0; q < 2; ++q) {
                const f32x4 a = (q == 0) ? a10 : a11;
                const float ig = sigf(a[0] + bs1[q][0]);
                const float fg = sigf(a[1] + bs1[q][1]);
                const float gg = tanhf(a[2] + bs1[q][2]);
                const float og = sigf(a[3] + bs1[q][3]);
                const float c = fg * cr1[q] + ig * gg;
                cr1[q] = c;
                cn1[q] = c; hn1[q] = og * tanhf(c);
            }
            char* h1w = wsb + H1S_OFF + (size_t)wr * 65536u;
            char* c1w = wsb + C1S_OFF + (size_t)(s & 3) * 65536u;
            #pragma unroll
            for (int q = 0; q < 2; ++q) {
                const float h0 = __shfl(hn1[q], lo), h1v = __shfl(hn1[q], 16 + lo);
                const float h2v = __shfl(hn1[q], 32 + lo), h3 = __shfl(hn1[q], 48 + lo);
                const float c0 = __shfl(cn1[q], lo), c1v = __shfl(cn1[q], 16 + lo);
                const float c2v = __shfl(cn1[q], 32 + lo), c3 = __shfl(cn1[q], 48 + lo);
                if (hi == q) {
                    const int cc = bk * 8 + q * 4;
                    const size_t ad = slab_waddr(cc, b);
                    astore8(h1w + ad, pack4h(h0, h1v, h2v, h3));
                    astore8(c1w + ad, pack4h(c0, c1v, c2v, c3));
                }
            }
        }
        // ======== POST-WAIT: L2 h2-part, step t = s-2 ========
        if (doL2) {
            const char* h2p = wsb + H2S_OFF + (size_t)rd * 90112u + (size_t)l * 16;
            half8 bh2[22];
            #pragma unroll
            for (int kk = 0; kk < 22; ++kk) bh2[kk] = ld_act(h2p + (size_t)(kk * 4 + wv) * 1024);
            #pragma unroll
            for (int kk = 0; kk < 22; ++kk) {
                const char* at = lds + L2W_OFF + (size_t)((16 + kk) * 3) * 1024 + (size_t)l * 16;
                a20 = __builtin_amdgcn_mfma_f32_16x16x32_f16(*(const half8*)(at       ), bh2[kk], a20, 0, 0, 0);
                a21 = __builtin_amdgcn_mfma_f32_16x16x32_f16(*(const half8*)(at + 1024), bh2[kk], a21, 0, 0, 0);
                a22 = __builtin_amdgcn_mfma_f32_16x16x32_f16(*(const half8*)(at + 2048), bh2[kk], a22, 0, 0, 0);
            }
            float cn2[3], hn2[3];
            #pragma unroll
            for (int q = 0; q < 3; ++q) {
                const f32x4 a = (q == 0) ? a20 : (q == 1) ? a21 : a22;
                const float ig = sigf(a[0] + bs2[q][0]);
                const float fg = sigf(a[1] + bs2[q][1]);
                const float gg = tanhf(a[2] + bs2[q][2]);
                const float og = sigf(a[3] + bs2[q][3]);
                const float c = fg * cr2[q] + ig * gg;
                cr2[q] = c;
                cn2[q] = c; hn2[q] = og * tanhf(c);
            }
            char* h2w = wsb + H2S_OFF + (size_t)wr * 90112u;
            #pragma unroll
            for (int q = 0; q < 3; ++q) {
                const float h0 = __shfl(hn2[q], lo), h1v = __shfl(hn2[q], 16 + lo);
                const float h2v = __shfl(hn2[q], 32 + lo), h3 = __shfl(hn2[q], 48 + lo);
                const float c0 = __shfl(cn2[q], lo), c1v = __shfl(cn2[q], 16 + lo);
                const float c2v = __shfl(cn2[q], 32 + lo), c3 = __shfl(cn2[q], 48 + lo);
                if (hi == q) {
                    const int cc = bk * 12 + q * 4;
                    if (cc + 4 <= OO) {
                        astore8(h2w + slab_waddr(cc, b), pack4h(h0, h1v, h2v, h3));
                        pend[0] = c0; pend[1] = c1v; pend[2] = c2v; pend[3] = c3;
                        pendP = out + (size_t)b * (TT * OO) + (size_t)(s - 2) * OO + cc;
                    }
                }
            }
        }
        // ---- single-hop arrival ----
        __syncthreads();   // drains all waves' slab stores
        if (s <= TT && tid == 0) astore32(bar + bk, (unsigned)(s + 1));
        // ---- deferred out store (HBM ack drains behind the next wait) ----
        if (pendP) {
            const f32x4 q4 = {pend[0], pend[1], pend[2], pend[3]};
            __builtin_nontemporal_store(q4, (f32x4*)pendP);
        }
    }
}

extern "C" void kernel_launch(void* const* d_in, const int* in_sizes, int n_in,
                              void* d_out, int out_size, void* d_ws, size_t ws_size,
                              hipStream_t stream)
{
    const float* data = (const float*)d_in[0];
    const float* Wih1 = (const float*)d_in[1];
    const float* Whh1 = (const float*)d_in[2];
    const float* bih1 = (const float*)d_in[3];
    const float* bhh1 = (const float*)d_in[4];
    const float* Wih2 = (const float*)d_in[5];
    const float* Whh2 = (const float*)d_in[6];
    const float* bih2 = (const float*)d_in[7];
    const float* bhh2 = (const float*)d_in[8];
    float* out = (float*)d_out;
    char* wsb  = (char*)d_ws;

    hipFuncSetAttribute((const void*)rnn_merged, hipFuncAttributeMaxDynamicSharedMemorySize, (int)LDS_BYTES);
    hipMemsetAsync(wsb, 0, MEMSET_BYTES, stream);   // slabs + epoch slots: replay-safe
    rnn_merged<<<NBLK, 256, LDS_BYTES, stream>>>(data,
                                                 Wih1, Whh1, bih1, bhh1,
                                                 Wih2, Whh2, bih2, bhh2,
                                                 wsb, out);
}